// Round 7
// baseline (302.352 us; speedup 1.0000x reference)
//
#include <hip/hip_runtime.h>
#include <math.h>

// Problem constants
#define NB 16
#define NT 200
#define ND 128
#define NH 4
#define NDK 32

typedef float f32x4 __attribute__((ext_vector_type(4)));

// ---------------------------------------------------------------------------
// Kernel 1: fused QKV projection.  q = query@Wq+bq etc.  4 rows per block.
// ---------------------------------------------------------------------------
__global__ __launch_bounds__(128) void qkv_proj_k(
    const float* __restrict__ query, const float* __restrict__ key_,
    const float* __restrict__ value,
    const float* __restrict__ Wq, const float* __restrict__ bq,
    const float* __restrict__ Wk, const float* __restrict__ bk,
    const float* __restrict__ Wv, const float* __restrict__ bv,
    float* __restrict__ qp, float* __restrict__ kp, float* __restrict__ vp)
{
    __shared__ float xq[4][128], xk[4][128], xv[4][128];
    int t = threadIdx.x;
    int g0 = blockIdx.x * 4;
    for (int r = 0; r < 4; ++r) {
        xq[r][t] = query[(size_t)(g0 + r) * ND + t];
        xk[r][t] = key_ [(size_t)(g0 + r) * ND + t];
        xv[r][t] = value[(size_t)(g0 + r) * ND + t];
    }
    __syncthreads();
    float aq[4], ak[4], av[4];
    for (int r = 0; r < 4; ++r) { aq[r] = bq[t]; ak[r] = bk[t]; av[r] = bv[t]; }
    for (int d = 0; d < 128; ++d) {
        float wq = Wq[d * ND + t], wk = Wk[d * ND + t], wv = Wv[d * ND + t];
        #pragma unroll
        for (int r = 0; r < 4; ++r) {
            aq[r] += xq[r][d] * wq;
            ak[r] += xk[r][d] * wk;
            av[r] += xv[r][d] * wv;
        }
    }
    for (int r = 0; r < 4; ++r) {
        qp[(size_t)(g0 + r) * ND + t] = aq[r];
        kp[(size_t)(g0 + r) * ND + t] = ak[r];
        vp[(size_t)(g0 + r) * ND + t] = av[r];
    }
}

// ---------------------------------------------------------------------------
// Kernel 2: abs-head prep.  qa = Xq_a + Pq, ka = Xk_a + Pk.
// ---------------------------------------------------------------------------
__global__ __launch_bounds__(128) void abs_prep_k(
    const float* __restrict__ absk,
    const float* __restrict__ aqw, const float* __restrict__ aqb,
    const float* __restrict__ akw, const float* __restrict__ akb,
    const float* __restrict__ qp, const float* __restrict__ kp,
    float* __restrict__ qa, float* __restrict__ ka)
{
    __shared__ float aks[8][2][128];
    int t = threadIdx.x;
    int g0 = blockIdx.x * 8;
    for (int idx = t; idx < 8 * 2 * 128; idx += 128) {
        int r  = idx >> 8;
        int h2 = (idx >> 7) & 1;
        int d  = idx & 127;
        int g = g0 + r; int b = g / NT; int i = g % NT;
        aks[r][h2][d] = absk[(((size_t)h2 * NB + b) * NT + i) * ND + d];
    }
    __syncthreads();
    int which = t >> 6;
    int h = (t >> 5) & 1;
    int o = t & 31;
    const float* w  = which ? akw : aqw;
    const float* bb = which ? akb : aqb;
    const float* xp = which ? kp  : qp;
    float bv = bb[h * NDK + o];
    float acc[8];
    for (int r = 0; r < 8; ++r) acc[r] = bv;
    for (int d = 0; d < 128; ++d) {
        float wv = w[((size_t)h * ND + d) * NDK + o];
        #pragma unroll
        for (int r = 0; r < 8; ++r) acc[r] += aks[r][h][d] * wv;
    }
    float* dst = which ? ka : qa;
    for (int r = 0; r < 8; ++r) {
        int g = g0 + r; int b = g / NT; int i = g % NT;
        float val = acc[r] + xp[(size_t)g * ND + h * NDK + o];
        dst[((size_t)(b * 2 + h) * NT + i) * NDK + o] = val;
    }
}

// ---------------------------------------------------------------------------
// Kernel 3: rel-head prep.
// u[b,h,i,d] = sum_o (Xq_r[b,h,i,o]+rel_bias[h,o]) * rel_k_w[h,d,o]
// c[b,h,i]   = sum_o (Xq_r[b,h,i,o]+rel_bias[h,o]) * rel_k_b[h,o]
// ---------------------------------------------------------------------------
__global__ __launch_bounds__(256) void rel_prep_k(
    const float* __restrict__ qp,
    const float* __restrict__ rkw, const float* __restrict__ rkb,
    const float* __restrict__ rbias,
    float* __restrict__ u, float* __restrict__ cb)
{
    __shared__ float qb[8][2][32];
    int t = threadIdx.x;
    int g0 = blockIdx.x * 8;
    for (int idx = t; idx < 8 * 2 * 32; idx += 256) {
        int r = idx >> 6; int h2 = (idx >> 5) & 1; int o = idx & 31;
        int g = g0 + r;
        qb[r][h2][o] = qp[(size_t)g * ND + (2 + h2) * NDK + o] + rbias[h2 * NDK + o];
    }
    __syncthreads();
    int h = t >> 7;
    int d = t & 127;
    float acc[8] = {0, 0, 0, 0, 0, 0, 0, 0};
    for (int o = 0; o < 32; ++o) {
        float wv = rkw[((size_t)h * ND + d) * NDK + o];
        #pragma unroll
        for (int r = 0; r < 8; ++r) acc[r] += qb[r][h][o] * wv;
    }
    for (int r = 0; r < 8; ++r) {
        int g = g0 + r; int b = g / NT; int i = g % NT;
        u[((size_t)(b * 2 + h) * NT + i) * ND + d] = acc[r];
    }
    if (d == 0) {
        for (int r = 0; r < 8; ++r) {
            float cc = 0.0f;
            for (int o = 0; o < 32; ++o) cc += qb[r][h][o] * rkb[h * NDK + o];
            int g = g0 + r; int b = g / NT; int i = g % NT;
            cb[(b * 2 + h) * NT + i] = cc;
        }
    }
}

// ---------------------------------------------------------------------------
// Kernel 4: fused scores + mask + softmax + PV.  One block per (b,h,i).
// MASK-AWARE rel stream, EXACT row count: all candidate row indices are
// pre-loaded into registers (static jr[5][5]); fully-unrolled chunk loop
// with per-load guards (idx < cnt, uniform per half-wave) streams exactly
// cnt unmasked rows — no tail waste, no LDS reads in the load path.
// ---------------------------------------------------------------------------
__global__ __launch_bounds__(256) void attn_core_k(
    const float* __restrict__ qp, const float* __restrict__ kp,
    const float* __restrict__ vp,
    const float* __restrict__ qa, const float* __restrict__ ka,
    const float* __restrict__ u,  const float* __restrict__ cb,
    const int* __restrict__ mask, const float* __restrict__ rel,
    float* __restrict__ xb)
{
    __shared__ float s[256];
    __shared__ float qrow[32];
    __shared__ float redm[4], reds[4];
    __shared__ float xred[256];
    __shared__ float part[200][9];   // stride-9: conflict-free
    __shared__ int   jlist[200];     // [0,cnt): unmasked j (ascending)
    __shared__ int   wc1[4], wc0[4];
    int t = threadIdx.x;
    int bx = blockIdx.x;
    int i  = bx % NT;
    int bh = bx / NT;
    int h  = bh % NH;
    int b  = bh / NH;
    bool isrel = (h >= 2);
    int hr = h - 2;
    int lane = t & 63, wvi = t >> 6;

    // ---- mask row + ballot-based compaction ----
    int mk = (t < NT) ? mask[((size_t)b * NT + i) * NT + t] : 0;
    bool valid = (t < NT);
    unsigned long long b1 = __ballot(valid && (mk != 0));
    unsigned long long b0 = __ballot(valid && (mk == 0));
    if (lane == 63) { wc1[wvi] = __popcll(b1); wc0[wvi] = __popcll(b0); }
    if (t < 32) {
        qrow[t] = isrel ? qp[((size_t)(b * NT + i)) * ND + h * NDK + t]
                        : qa[((size_t)(b * 2 + h) * NT + i) * NDK + t];
    }
    __syncthreads();
    unsigned long long below = ((unsigned long long)1 << lane) - 1;
    int off1 = 0, off0 = 0, cnt = 0;
    #pragma unroll
    for (int w2 = 0; w2 < 4; ++w2) {
        int c1 = wc1[w2], c0 = wc0[w2];
        if (w2 < wvi) { off1 += c1; off0 += c0; }
        cnt += c1;
    }
    if (valid) {
        if (mk) jlist[off1 + __popcll(b1 & below)] = t;
        else    jlist[cnt + off0 + __popcll(b0 & below)] = t;
    }
    __syncthreads();

    // ---- K-dot: s[j] = q . k_j (+ c bias for rel heads) ----
    float cval = isrel ? cb[(b * 2 + hr) * NT + i] : 0.0f;
    if (t < NT) {
        const float* krow = isrel ? (kp + ((size_t)(b * NT + t)) * ND + h * NDK)
                                  : (ka + ((size_t)(b * 2 + h) * NT + t) * NDK);
        const float4* k4 = (const float4*)krow;
        const float4* q4 = (const float4*)qrow;
        float acc = cval;
        #pragma unroll
        for (int q = 0; q < 8; ++q) {
            float4 kv = k4[q]; float4 qv = q4[q];
            acc += kv.x * qv.x + kv.y * qv.y + kv.z * qv.z + kv.w * qv.w;
        }
        s[t] = acc;
    } else {
        s[t] = -INFINITY;
    }

    // ---- rel stream: exactly cnt rows, indices register-resident ----
    if (isrel) {
        int half = (lane >> 5), l32 = t & 31;
        int grp = wvi * 2 + half;          // 0..7
        const f32x4* u4g = (const f32x4*)(u + ((size_t)(b * 2 + hr) * NT + i) * ND);
        f32x4 ur = u4g[l32];
        const f32x4* rel4 =
            (const f32x4*)(rel + ((((size_t)hr * NB + b) * NT + i) * (size_t)NT) * ND);

        // Pre-load all candidate indices for this grp (broadcast LDS reads,
        // statically indexed -> registers).
        int jr[5][5];
        #pragma unroll
        for (int cc = 0; cc < 5; ++cc)
            #pragma unroll
            for (int n = 0; n < 5; ++n) {
                int idx = cc * 40 + grp + 8 * n;
                jr[cc][n] = jlist[idx < 200 ? idx : 199];
            }

        #pragma unroll
        for (int cc = 0; cc < 5; ++cc) {
            int base = cc * 40;
            if (base < cnt) {
                f32x4 rv[5];
                #pragma unroll
                for (int n = 0; n < 5; ++n)
                    if (base + grp + 8 * n < cnt)
                        rv[n] = __builtin_nontemporal_load(
                            rel4 + (size_t)jr[cc][n] * 32 + l32);
                #pragma unroll
                for (int n = 0; n < 5; ++n)
                    if (base + grp + 8 * n < cnt) {
                        float p = rv[n].x * ur.x + rv[n].y * ur.y
                                + rv[n].z * ur.z + rv[n].w * ur.w;
                        p += __shfl_xor(p, 16, 32);
                        p += __shfl_xor(p, 8, 32);
                        if (l32 < 8) part[jr[cc][n]][l32] = p;
                    }
            }
        }
        __syncthreads();
        if (t < NT && mk != 0) {   // masked rows skip (part[] stale there)
            s[t] += part[t][0] + part[t][1] + part[t][2] + part[t][3]
                  + part[t][4] + part[t][5] + part[t][6] + part[t][7];
        }
    }
    __syncthreads();

    // ---- scale then mask (matches reference order) ----
    if (t < NT) {
        float val = s[t] * 0.17677669529663687f;   // 1/sqrt(32)
        if (mk == 0) val = -1.0e9f;
        s[t] = val;
    }
    __syncthreads();

    // ---- softmax over 256 slots (pad = -inf -> exp 0) ----
    float sv = s[t];
    float m = sv;
    #pragma unroll
    for (int dd = 32; dd >= 1; dd >>= 1) m = fmaxf(m, __shfl_xor(m, dd, 64));
    if ((t & 63) == 0) redm[t >> 6] = m;
    __syncthreads();
    m = fmaxf(fmaxf(redm[0], redm[1]), fmaxf(redm[2], redm[3]));
    float e = expf(sv - m);
    float ssum = e;
    #pragma unroll
    for (int dd = 32; dd >= 1; dd >>= 1) ssum += __shfl_xor(ssum, dd, 64);
    if ((t & 63) == 0) reds[t >> 6] = ssum;
    __syncthreads();
    float tot = reds[0] + reds[1] + reds[2] + reds[3];
    s[t] = e / tot;
    __syncthreads();

    // ---- PV: x[o] = sum_j p[j] * v[b, j, h*32+o] ----
    int o = t & 31, g = t >> 5;
    float acc2 = 0.0f;
    const float* vb = vp + (size_t)b * NT * ND + h * NDK + o;
    for (int j = g; j < NT; j += 8) acc2 += s[j] * vb[(size_t)j * ND];
    xred[t] = acc2;
    __syncthreads();
    if (t < 32) {
        float r = 0.0f;
        #pragma unroll
        for (int g2 = 0; g2 < 8; ++g2) r += xred[g2 * 32 + t];
        xb[((size_t)(b * NT + i)) * ND + h * NDK + t] = r;
    }
}

// ---------------------------------------------------------------------------
// Kernel 5: output projection.  out = xb @ Wo + bo.
// ---------------------------------------------------------------------------
__global__ __launch_bounds__(128) void out_proj_k(
    const float* __restrict__ xb, const float* __restrict__ Wo,
    const float* __restrict__ bo, float* __restrict__ out)
{
    __shared__ float xs[4][128];
    int t = threadIdx.x;
    int g0 = blockIdx.x * 4;
    for (int r = 0; r < 4; ++r) xs[r][t] = xb[(size_t)(g0 + r) * ND + t];
    __syncthreads();
    float bb = bo[t];
    float acc[4];
    for (int r = 0; r < 4; ++r) acc[r] = bb;
    for (int d = 0; d < 128; ++d) {
        float wv = Wo[d * ND + t];
        #pragma unroll
        for (int r = 0; r < 4; ++r) acc[r] += xs[r][d] * wv;
    }
    for (int r = 0; r < 4; ++r) out[(size_t)(g0 + r) * ND + t] = acc[r];
}

// ---------------------------------------------------------------------------
extern "C" void kernel_launch(void* const* d_in, const int* in_sizes, int n_in,
                              void* d_out, int out_size, void* d_ws, size_t ws_size,
                              hipStream_t stream)
{
    const float* query = (const float*)d_in[0];
    const float* key_  = (const float*)d_in[1];
    const float* value = (const float*)d_in[2];
    const int*   mask  = (const int*)  d_in[3];
    const float* rel   = (const float*)d_in[4];
    const float* absk  = (const float*)d_in[5];
    // d_in[6] = layer (unused by reference)
    const float* Wq = (const float*)d_in[7];
    const float* bq = (const float*)d_in[8];
    const float* Wk = (const float*)d_in[9];
    const float* bk = (const float*)d_in[10];
    const float* Wv = (const float*)d_in[11];
    const float* bv = (const float*)d_in[12];
    const float* aqw = (const float*)d_in[13];
    const float* aqb = (const float*)d_in[14];
    const float* akw = (const float*)d_in[15];
    const float* akb = (const float*)d_in[16];
    const float* rkw = (const float*)d_in[17];
    const float* rkb = (const float*)d_in[18];
    const float* rbias = (const float*)d_in[19];
    const float* Wo = (const float*)d_in[20];
    const float* bo = (const float*)d_in[21];
    float* out = (float*)d_out;

    // workspace layout (floats)
    float* qp = (float*)d_ws;          // 409600  (B,T,D)
    float* kp = qp + 409600;           // 409600
    float* vp = kp + 409600;           // 409600
    float* qa = vp + 409600;           // 204800  (B,2,T,32)
    float* ka = qa + 204800;           // 204800
    float* ub = ka + 204800;           // 819200  (B,2,T,128)
    float* cbw = ub + 819200;          // 6400    (B,2,T)
    float* xb = cbw + 6400;            // 409600  (B,T,D)

    qkv_proj_k<<<NB * NT / 4, 128, 0, stream>>>(query, key_, value,
                                                Wq, bq, Wk, bk, Wv, bv,
                                                qp, kp, vp);
    abs_prep_k<<<NB * NT / 8, 128, 0, stream>>>(absk, aqw, aqb, akw, akb,
                                                qp, kp, qa, ka);
    rel_prep_k<<<NB * NT / 8, 256, 0, stream>>>(qp, rkw, rkb, rbias, ub, cbw);
    attn_core_k<<<NB * NH * NT, 256, 0, stream>>>(qp, kp, vp, qa, ka, ub, cbw,
                                                  mask, rel, xb);
    out_proj_k<<<NB * NT / 4, 128, 0, stream>>>(xb, Wo, bo, out);
}

// Round 8
// 227.243 us; speedup vs baseline: 1.3305x; 1.3305x over previous
//
#include <hip/hip_runtime.h>
#include <math.h>

// Problem constants
#define NB 16
#define NT 200
#define ND 128
#define NH 4
#define NDK 32

typedef float f32x4 __attribute__((ext_vector_type(4)));

// ---------------------------------------------------------------------------
// Kernel 1: fused QKV projection.  q = query@Wq+bq etc.  4 rows per block.
// ---------------------------------------------------------------------------
__global__ __launch_bounds__(128) void qkv_proj_k(
    const float* __restrict__ query, const float* __restrict__ key_,
    const float* __restrict__ value,
    const float* __restrict__ Wq, const float* __restrict__ bq,
    const float* __restrict__ Wk, const float* __restrict__ bk,
    const float* __restrict__ Wv, const float* __restrict__ bv,
    float* __restrict__ qp, float* __restrict__ kp, float* __restrict__ vp)
{
    __shared__ float xq[4][128], xk[4][128], xv[4][128];
    int t = threadIdx.x;
    int g0 = blockIdx.x * 4;
    for (int r = 0; r < 4; ++r) {
        xq[r][t] = query[(size_t)(g0 + r) * ND + t];
        xk[r][t] = key_ [(size_t)(g0 + r) * ND + t];
        xv[r][t] = value[(size_t)(g0 + r) * ND + t];
    }
    __syncthreads();
    float aq[4], ak[4], av[4];
    for (int r = 0; r < 4; ++r) { aq[r] = bq[t]; ak[r] = bk[t]; av[r] = bv[t]; }
    for (int d = 0; d < 128; ++d) {
        float wq = Wq[d * ND + t], wk = Wk[d * ND + t], wv = Wv[d * ND + t];
        #pragma unroll
        for (int r = 0; r < 4; ++r) {
            aq[r] += xq[r][d] * wq;
            ak[r] += xk[r][d] * wk;
            av[r] += xv[r][d] * wv;
        }
    }
    for (int r = 0; r < 4; ++r) {
        qp[(size_t)(g0 + r) * ND + t] = aq[r];
        kp[(size_t)(g0 + r) * ND + t] = ak[r];
        vp[(size_t)(g0 + r) * ND + t] = av[r];
    }
}

// ---------------------------------------------------------------------------
// Kernel 2: abs-head prep.  qa = Xq_a + Pq, ka = Xk_a + Pk.
// ---------------------------------------------------------------------------
__global__ __launch_bounds__(128) void abs_prep_k(
    const float* __restrict__ absk,
    const float* __restrict__ aqw, const float* __restrict__ aqb,
    const float* __restrict__ akw, const float* __restrict__ akb,
    const float* __restrict__ qp, const float* __restrict__ kp,
    float* __restrict__ qa, float* __restrict__ ka)
{
    __shared__ float aks[8][2][128];
    int t = threadIdx.x;
    int g0 = blockIdx.x * 8;
    for (int idx = t; idx < 8 * 2 * 128; idx += 128) {
        int r  = idx >> 8;
        int h2 = (idx >> 7) & 1;
        int d  = idx & 127;
        int g = g0 + r; int b = g / NT; int i = g % NT;
        aks[r][h2][d] = absk[(((size_t)h2 * NB + b) * NT + i) * ND + d];
    }
    __syncthreads();
    int which = t >> 6;
    int h = (t >> 5) & 1;
    int o = t & 31;
    const float* w  = which ? akw : aqw;
    const float* bb = which ? akb : aqb;
    const float* xp = which ? kp  : qp;
    float bv = bb[h * NDK + o];
    float acc[8];
    for (int r = 0; r < 8; ++r) acc[r] = bv;
    for (int d = 0; d < 128; ++d) {
        float wv = w[((size_t)h * ND + d) * NDK + o];
        #pragma unroll
        for (int r = 0; r < 8; ++r) acc[r] += aks[r][h][d] * wv;
    }
    float* dst = which ? ka : qa;
    for (int r = 0; r < 8; ++r) {
        int g = g0 + r; int b = g / NT; int i = g % NT;
        float val = acc[r] + xp[(size_t)g * ND + h * NDK + o];
        dst[((size_t)(b * 2 + h) * NT + i) * NDK + o] = val;
    }
}

// ---------------------------------------------------------------------------
// Kernel 3: rel-head prep.
// u[b,h,i,d] = sum_o (Xq_r[b,h,i,o]+rel_bias[h,o]) * rel_k_w[h,d,o]
// c[b,h,i]   = sum_o (Xq_r[b,h,i,o]+rel_bias[h,o]) * rel_k_b[h,o]
// ---------------------------------------------------------------------------
__global__ __launch_bounds__(256) void rel_prep_k(
    const float* __restrict__ qp,
    const float* __restrict__ rkw, const float* __restrict__ rkb,
    const float* __restrict__ rbias,
    float* __restrict__ u, float* __restrict__ cb)
{
    __shared__ float qb[8][2][32];
    int t = threadIdx.x;
    int g0 = blockIdx.x * 8;
    for (int idx = t; idx < 8 * 2 * 32; idx += 256) {
        int r = idx >> 6; int h2 = (idx >> 5) & 1; int o = idx & 31;
        int g = g0 + r;
        qb[r][h2][o] = qp[(size_t)g * ND + (2 + h2) * NDK + o] + rbias[h2 * NDK + o];
    }
    __syncthreads();
    int h = t >> 7;
    int d = t & 127;
    float acc[8] = {0, 0, 0, 0, 0, 0, 0, 0};
    for (int o = 0; o < 32; ++o) {
        float wv = rkw[((size_t)h * ND + d) * NDK + o];
        #pragma unroll
        for (int r = 0; r < 8; ++r) acc[r] += qb[r][h][o] * wv;
    }
    for (int r = 0; r < 8; ++r) {
        int g = g0 + r; int b = g / NT; int i = g % NT;
        u[((size_t)(b * 2 + h) * NT + i) * ND + d] = acc[r];
    }
    if (d == 0) {
        for (int r = 0; r < 8; ++r) {
            float cc = 0.0f;
            for (int o = 0; o < 32; ++o) cc += qb[r][h][o] * rkb[h * NDK + o];
            int g = g0 + r; int b = g / NT; int i = g % NT;
            cb[(b * 2 + h) * NT + i] = cc;
        }
    }
}

// ---------------------------------------------------------------------------
// Kernel 4: fused attention, ONE BLOCK PER (b,i) — all 4 heads (wave w = head
// w).  Mask load + compaction once per block; both rel heads share jlist and
// stream in one pass (R6's proven 5-deep nt-batch inner loop); softmax is
// per-wave shfl-only (no barriers); PV per wave.  3 block barriers total.
// ---------------------------------------------------------------------------
__global__ __launch_bounds__(256) void attn_core_k(
    const float* __restrict__ qp, const float* __restrict__ kp,
    const float* __restrict__ vp,
    const float* __restrict__ qa, const float* __restrict__ ka,
    const float* __restrict__ u,  const float* __restrict__ cb,
    const int* __restrict__ mask, const float* __restrict__ rel,
    float* __restrict__ xb)
{
    __shared__ float s[4][256];        // scores, then p_attn
    __shared__ float qrow[4][32];
    __shared__ float part[2][200][9];  // rel partials, stride-9 conflict-free
    __shared__ int   jlist[200];       // [0,cnt): unmasked j (ascending)
    __shared__ int   mrow[200];
    __shared__ int   wc1[4], wc0[4];
    int t = threadIdx.x;
    int bx = blockIdx.x;               // b*NT + i
    int i  = bx % NT;
    int b  = bx / NT;
    int lane = t & 63, wv = t >> 6;

    // ---- mask row + ballot counts + q rows ----
    int mk = (t < NT) ? mask[((size_t)b * NT + i) * NT + t] : 0;
    bool valid = (t < NT);
    unsigned long long b1 = __ballot(valid && (mk != 0));
    unsigned long long b0 = __ballot(valid && (mk == 0));
    if (lane == 63) { wc1[wv] = __popcll(b1); wc0[wv] = __popcll(b0); }
    if (valid) mrow[t] = mk;
    if (t < 128) {
        int h = t >> 5, o = t & 31;
        qrow[h][o] = (h < 2)
            ? qa[((size_t)(b * 2 + h) * NT + i) * NDK + o]
            : qp[((size_t)(b * NT + i)) * ND + h * NDK + o];
    }
    __syncthreads();

    // ---- prefix scan -> compacted jlist ----
    unsigned long long below = ((unsigned long long)1 << lane) - 1;
    int off1 = 0, off0 = 0, cnt = 0;
    #pragma unroll
    for (int w2 = 0; w2 < 4; ++w2) {
        int c1 = wc1[w2], c0 = wc0[w2];
        if (w2 < wv) { off1 += c1; off0 += c0; }
        cnt += c1;
    }
    if (valid) {
        if (mk) jlist[off1 + __popcll(b1 & below)] = t;
        else    jlist[cnt + off0 + __popcll(b0 & below)] = t;
    }
    __syncthreads();

    // ---- K-dot: wave wv = head wv, lanes cover j ----
    {
        int hh = wv;
        float cval = (hh >= 2) ? cb[(b * 2 + (hh - 2)) * NT + i] : 0.0f;
        float4 qv[8];
        const float4* q4 = (const float4*)qrow[hh];
        #pragma unroll
        for (int q = 0; q < 8; ++q) qv[q] = q4[q];
        #pragma unroll
        for (int it = 0; it < 4; ++it) {
            int j = lane + 64 * it;
            if (j < NT) {
                const float* krow = (hh < 2)
                    ? (ka + ((size_t)(b * 2 + hh) * NT + j) * NDK)
                    : (kp + ((size_t)(b * NT + j)) * ND + hh * NDK);
                const float4* k4 = (const float4*)krow;
                float acc = cval;
                #pragma unroll
                for (int q = 0; q < 8; ++q) {
                    float4 kv = k4[q];
                    acc += kv.x*qv[q].x + kv.y*qv[q].y + kv.z*qv[q].z + kv.w*qv[q].w;
                }
                s[hh][j] = acc;
            }
        }
    }

    // ---- rel stream: both rel heads, compacted rows (R6 inner loop) ----
    {
        int half = (lane >> 5), l32 = t & 31;
        int grp = wv * 2 + half;          // 0..7
        const f32x4* u40 = (const f32x4*)(u + ((size_t)(b * 2 + 0) * NT + i) * ND);
        const f32x4* u41 = (const f32x4*)(u + ((size_t)(b * 2 + 1) * NT + i) * ND);
        f32x4 ur0 = u40[l32], ur1 = u41[l32];
        #pragma unroll 1
        for (int hr = 0; hr < 2; ++hr) {
            f32x4 ur = hr ? ur1 : ur0;
            const f32x4* rel4 = (const f32x4*)
                (rel + ((((size_t)hr * NB + b) * NT + i) * (size_t)NT) * ND);
            float (*pp)[9] = part[hr];
            #pragma unroll 1
            for (int base = 0; base < cnt; base += 40) {
                int j0 = jlist[base + grp];
                int j1 = jlist[base + grp + 8];
                int j2 = jlist[base + grp + 16];
                int j3 = jlist[base + grp + 24];
                int j4 = jlist[base + grp + 32];
                f32x4 rv0 = __builtin_nontemporal_load(rel4 + (size_t)j0 * 32 + l32);
                f32x4 rv1 = __builtin_nontemporal_load(rel4 + (size_t)j1 * 32 + l32);
                f32x4 rv2 = __builtin_nontemporal_load(rel4 + (size_t)j2 * 32 + l32);
                f32x4 rv3 = __builtin_nontemporal_load(rel4 + (size_t)j3 * 32 + l32);
                f32x4 rv4 = __builtin_nontemporal_load(rel4 + (size_t)j4 * 32 + l32);
                float p0 = rv0.x*ur.x + rv0.y*ur.y + rv0.z*ur.z + rv0.w*ur.w;
                p0 += __shfl_xor(p0, 16, 32); p0 += __shfl_xor(p0, 8, 32);
                if (l32 < 8) pp[j0][l32] = p0;
                float p1 = rv1.x*ur.x + rv1.y*ur.y + rv1.z*ur.z + rv1.w*ur.w;
                p1 += __shfl_xor(p1, 16, 32); p1 += __shfl_xor(p1, 8, 32);
                if (l32 < 8) pp[j1][l32] = p1;
                float p2 = rv2.x*ur.x + rv2.y*ur.y + rv2.z*ur.z + rv2.w*ur.w;
                p2 += __shfl_xor(p2, 16, 32); p2 += __shfl_xor(p2, 8, 32);
                if (l32 < 8) pp[j2][l32] = p2;
                float p3 = rv3.x*ur.x + rv3.y*ur.y + rv3.z*ur.z + rv3.w*ur.w;
                p3 += __shfl_xor(p3, 16, 32); p3 += __shfl_xor(p3, 8, 32);
                if (l32 < 8) pp[j3][l32] = p3;
                float p4 = rv4.x*ur.x + rv4.y*ur.y + rv4.z*ur.z + rv4.w*ur.w;
                p4 += __shfl_xor(p4, 16, 32); p4 += __shfl_xor(p4, 8, 32);
                if (l32 < 8) pp[j4][l32] = p4;
            }
        }
    }
    __syncthreads();

    // ---- finish scores + per-wave softmax (wave wv = head wv) ----
    {
        int hh = wv;
        float pj[4];
        #pragma unroll
        for (int it = 0; it < 4; ++it) {
            int j = lane + 64 * it;
            float v = -INFINITY;
            if (j < NT) {
                float sv = s[hh][j];
                if (hh >= 2 && mrow[j] != 0) {
                    const float* pr = part[hh - 2][j];
                    sv += pr[0] + pr[1] + pr[2] + pr[3]
                        + pr[4] + pr[5] + pr[6] + pr[7];
                }
                sv *= 0.17677669529663687f;   // 1/sqrt(32)
                if (mrow[j] == 0) sv = -1.0e9f;
                v = sv;
            }
            pj[it] = v;
        }
        float m = fmaxf(fmaxf(pj[0], pj[1]), fmaxf(pj[2], pj[3]));
        #pragma unroll
        for (int d = 32; d >= 1; d >>= 1) m = fmaxf(m, __shfl_xor(m, d, 64));
        float e0 = expf(pj[0] - m), e1 = expf(pj[1] - m);
        float e2 = expf(pj[2] - m), e3 = expf(pj[3] - m);
        float tot = e0 + e1 + e2 + e3;
        #pragma unroll
        for (int d = 32; d >= 1; d >>= 1) tot += __shfl_xor(tot, d, 64);
        float ee[4] = {e0, e1, e2, e3};
        #pragma unroll
        for (int it = 0; it < 4; ++it) {
            int j = lane + 64 * it;
            if (j < NT) s[hh][j] = ee[it] / tot;
        }
    }
    __syncthreads();

    // ---- PV: wave wv = head wv; lane = (jhalf, o) ----
    {
        int hh = wv;
        int o = lane & 31, jh = lane >> 5;
        float acc = 0.0f;
        const float* vb = vp + (size_t)b * NT * ND + hh * NDK + o;
        for (int j = jh; j < NT; j += 2)
            acc += s[hh][j] * vb[(size_t)j * ND];
        acc += __shfl_xor(acc, 32, 64);
        if (jh == 0)
            xb[((size_t)(b * NT + i)) * ND + hh * NDK + o] = acc;
    }
}

// ---------------------------------------------------------------------------
// Kernel 5: output projection.  out = xb @ Wo + bo.
// ---------------------------------------------------------------------------
__global__ __launch_bounds__(128) void out_proj_k(
    const float* __restrict__ xb, const float* __restrict__ Wo,
    const float* __restrict__ bo, float* __restrict__ out)
{
    __shared__ float xs[4][128];
    int t = threadIdx.x;
    int g0 = blockIdx.x * 4;
    for (int r = 0; r < 4; ++r) xs[r][t] = xb[(size_t)(g0 + r) * ND + t];
    __syncthreads();
    float bb = bo[t];
    float acc[4];
    for (int r = 0; r < 4; ++r) acc[r] = bb;
    for (int d = 0; d < 128; ++d) {
        float wv = Wo[d * ND + t];
        #pragma unroll
        for (int r = 0; r < 4; ++r) acc[r] += xs[r][d] * wv;
    }
    for (int r = 0; r < 4; ++r) out[(size_t)(g0 + r) * ND + t] = acc[r];
}

// ---------------------------------------------------------------------------
extern "C" void kernel_launch(void* const* d_in, const int* in_sizes, int n_in,
                              void* d_out, int out_size, void* d_ws, size_t ws_size,
                              hipStream_t stream)
{
    const float* query = (const float*)d_in[0];
    const float* key_  = (const float*)d_in[1];
    const float* value = (const float*)d_in[2];
    const int*   mask  = (const int*)  d_in[3];
    const float* rel   = (const float*)d_in[4];
    const float* absk  = (const float*)d_in[5];
    // d_in[6] = layer (unused by reference)
    const float* Wq = (const float*)d_in[7];
    const float* bq = (const float*)d_in[8];
    const float* Wk = (const float*)d_in[9];
    const float* bk = (const float*)d_in[10];
    const float* Wv = (const float*)d_in[11];
    const float* bv = (const float*)d_in[12];
    const float* aqw = (const float*)d_in[13];
    const float* aqb = (const float*)d_in[14];
    const float* akw = (const float*)d_in[15];
    const float* akb = (const float*)d_in[16];
    const float* rkw = (const float*)d_in[17];
    const float* rkb = (const float*)d_in[18];
    const float* rbias = (const float*)d_in[19];
    const float* Wo = (const float*)d_in[20];
    const float* bo = (const float*)d_in[21];
    float* out = (float*)d_out;

    // workspace layout (floats)
    float* qp = (float*)d_ws;          // 409600  (B,T,D)
    float* kp = qp + 409600;           // 409600
    float* vp = kp + 409600;           // 409600
    float* qa = vp + 409600;           // 204800  (B,2,T,32)
    float* ka = qa + 204800;           // 204800
    float* ub = ka + 204800;           // 819200  (B,2,T,128)
    float* cbw = ub + 819200;          // 6400    (B,2,T)
    float* xb = cbw + 6400;            // 409600  (B,T,D)

    qkv_proj_k<<<NB * NT / 4, 128, 0, stream>>>(query, key_, value,
                                                Wq, bq, Wk, bk, Wv, bv,
                                                qp, kp, vp);
    abs_prep_k<<<NB * NT / 8, 128, 0, stream>>>(absk, aqw, aqb, akw, akb,
                                                qp, kp, qa, ka);
    rel_prep_k<<<NB * NT / 8, 256, 0, stream>>>(qp, rkw, rkb, rbias, ub, cbw);
    attn_core_k<<<NB * NT, 256, 0, stream>>>(qp, kp, vp, qa, ka, ub, cbw,
                                             mask, rel, xb);
    out_proj_k<<<NB * NT / 4, 128, 0, stream>>>(xb, Wo, bo, out);
}

// Round 9
// 204.252 us; speedup vs baseline: 1.4803x; 1.1126x over previous
//
#include <hip/hip_runtime.h>
#include <math.h>

// Problem constants
#define NB 16
#define NT 200
#define ND 128
#define NH 4
#define NDK 32

typedef float f32x4 __attribute__((ext_vector_type(4)));

// ---------------------------------------------------------------------------
// Kernel 1: fused QKV projection.  q = query@Wq+bq etc.  4 rows per block.
// ---------------------------------------------------------------------------
__global__ __launch_bounds__(128) void qkv_proj_k(
    const float* __restrict__ query, const float* __restrict__ key_,
    const float* __restrict__ value,
    const float* __restrict__ Wq, const float* __restrict__ bq,
    const float* __restrict__ Wk, const float* __restrict__ bk,
    const float* __restrict__ Wv, const float* __restrict__ bv,
    float* __restrict__ qp, float* __restrict__ kp, float* __restrict__ vp)
{
    __shared__ float xq[4][128], xk[4][128], xv[4][128];
    int t = threadIdx.x;
    int g0 = blockIdx.x * 4;
    for (int r = 0; r < 4; ++r) {
        xq[r][t] = query[(size_t)(g0 + r) * ND + t];
        xk[r][t] = key_ [(size_t)(g0 + r) * ND + t];
        xv[r][t] = value[(size_t)(g0 + r) * ND + t];
    }
    __syncthreads();
    float aq[4], ak[4], av[4];
    for (int r = 0; r < 4; ++r) { aq[r] = bq[t]; ak[r] = bk[t]; av[r] = bv[t]; }
    for (int d = 0; d < 128; ++d) {
        float wq = Wq[d * ND + t], wk = Wk[d * ND + t], wv = Wv[d * ND + t];
        #pragma unroll
        for (int r = 0; r < 4; ++r) {
            aq[r] += xq[r][d] * wq;
            ak[r] += xk[r][d] * wk;
            av[r] += xv[r][d] * wv;
        }
    }
    for (int r = 0; r < 4; ++r) {
        qp[(size_t)(g0 + r) * ND + t] = aq[r];
        kp[(size_t)(g0 + r) * ND + t] = ak[r];
        vp[(size_t)(g0 + r) * ND + t] = av[r];
    }
}

// ---------------------------------------------------------------------------
// Kernel 2: abs-head prep.  qa = Xq_a + Pq, ka = Xk_a + Pk.
// ---------------------------------------------------------------------------
__global__ __launch_bounds__(128) void abs_prep_k(
    const float* __restrict__ absk,
    const float* __restrict__ aqw, const float* __restrict__ aqb,
    const float* __restrict__ akw, const float* __restrict__ akb,
    const float* __restrict__ qp, const float* __restrict__ kp,
    float* __restrict__ qa, float* __restrict__ ka)
{
    __shared__ float aks[8][2][128];
    int t = threadIdx.x;
    int g0 = blockIdx.x * 8;
    for (int idx = t; idx < 8 * 2 * 128; idx += 128) {
        int r  = idx >> 8;
        int h2 = (idx >> 7) & 1;
        int d  = idx & 127;
        int g = g0 + r; int b = g / NT; int i = g % NT;
        aks[r][h2][d] = absk[(((size_t)h2 * NB + b) * NT + i) * ND + d];
    }
    __syncthreads();
    int which = t >> 6;
    int h = (t >> 5) & 1;
    int o = t & 31;
    const float* w  = which ? akw : aqw;
    const float* bb = which ? akb : aqb;
    const float* xp = which ? kp  : qp;
    float bv = bb[h * NDK + o];
    float acc[8];
    for (int r = 0; r < 8; ++r) acc[r] = bv;
    for (int d = 0; d < 128; ++d) {
        float wv = w[((size_t)h * ND + d) * NDK + o];
        #pragma unroll
        for (int r = 0; r < 8; ++r) acc[r] += aks[r][h][d] * wv;
    }
    float* dst = which ? ka : qa;
    for (int r = 0; r < 8; ++r) {
        int g = g0 + r; int b = g / NT; int i = g % NT;
        float val = acc[r] + xp[(size_t)g * ND + h * NDK + o];
        dst[((size_t)(b * 2 + h) * NT + i) * NDK + o] = val;
    }
}

// ---------------------------------------------------------------------------
// Kernel 3: rel-head prep.
// u[b,h,i,d] = sum_o (Xq_r[b,h,i,o]+rel_bias[h,o]) * rel_k_w[h,d,o]
// c[b,h,i]   = sum_o (Xq_r[b,h,i,o]+rel_bias[h,o]) * rel_k_b[h,o]
// ---------------------------------------------------------------------------
__global__ __launch_bounds__(256) void rel_prep_k(
    const float* __restrict__ qp,
    const float* __restrict__ rkw, const float* __restrict__ rkb,
    const float* __restrict__ rbias,
    float* __restrict__ u, float* __restrict__ cb)
{
    __shared__ float qb[8][2][32];
    int t = threadIdx.x;
    int g0 = blockIdx.x * 8;
    for (int idx = t; idx < 8 * 2 * 32; idx += 256) {
        int r = idx >> 6; int h2 = (idx >> 5) & 1; int o = idx & 31;
        int g = g0 + r;
        qb[r][h2][o] = qp[(size_t)g * ND + (2 + h2) * NDK + o] + rbias[h2 * NDK + o];
    }
    __syncthreads();
    int h = t >> 7;
    int d = t & 127;
    float acc[8] = {0, 0, 0, 0, 0, 0, 0, 0};
    for (int o = 0; o < 32; ++o) {
        float wv = rkw[((size_t)h * ND + d) * NDK + o];
        #pragma unroll
        for (int r = 0; r < 8; ++r) acc[r] += qb[r][h][o] * wv;
    }
    for (int r = 0; r < 8; ++r) {
        int g = g0 + r; int b = g / NT; int i = g % NT;
        u[((size_t)(b * 2 + h) * NT + i) * ND + d] = acc[r];
    }
    if (d == 0) {
        for (int r = 0; r < 8; ++r) {
            float cc = 0.0f;
            for (int o = 0; o < 32; ++o) cc += qb[r][h][o] * rkb[h * NDK + o];
            int g = g0 + r; int b = g / NT; int i = g % NT;
            cb[(b * 2 + h) * NT + i] = cc;
        }
    }
}

// ---------------------------------------------------------------------------
// Kernel 4: fused scores + mask + softmax + PV.  One block per (b,h,i).
// MASK-AWARE rel stream (R6 structure), EXACT byte count: full unguarded
// chunks of 40 while base+40 <= cnt, then a short guarded per-group tail
// (depth-1 loads, <=5 iters).  Streams exactly cnt unmasked rows.
// ---------------------------------------------------------------------------
__global__ __launch_bounds__(256) void attn_core_k(
    const float* __restrict__ qp, const float* __restrict__ kp,
    const float* __restrict__ vp,
    const float* __restrict__ qa, const float* __restrict__ ka,
    const float* __restrict__ u,  const float* __restrict__ cb,
    const int* __restrict__ mask, const float* __restrict__ rel,
    float* __restrict__ xb)
{
    __shared__ float s[256];
    __shared__ float qrow[32];
    __shared__ float redm[4], reds[4];
    __shared__ float xred[256];
    __shared__ float part[200][9];   // stride-9: conflict-free
    __shared__ int   jlist[200];     // [0,cnt): unmasked j (ascending)
    __shared__ int   wc1[4], wc0[4];
    int t = threadIdx.x;
    int bx = blockIdx.x;
    int i  = bx % NT;
    int bh = bx / NT;
    int h  = bh % NH;
    int b  = bh / NH;
    bool isrel = (h >= 2);
    int hr = h - 2;
    int lane = t & 63, wvi = t >> 6;

    // ---- mask row + ballot-based compaction ----
    int mk = (t < NT) ? mask[((size_t)b * NT + i) * NT + t] : 0;
    bool valid = (t < NT);
    unsigned long long b1 = __ballot(valid && (mk != 0));
    unsigned long long b0 = __ballot(valid && (mk == 0));
    if (lane == 63) { wc1[wvi] = __popcll(b1); wc0[wvi] = __popcll(b0); }
    if (t < 32) {
        qrow[t] = isrel ? qp[((size_t)(b * NT + i)) * ND + h * NDK + t]
                        : qa[((size_t)(b * 2 + h) * NT + i) * NDK + t];
    }
    __syncthreads();
    unsigned long long below = ((unsigned long long)1 << lane) - 1;
    int off1 = 0, off0 = 0, cnt = 0;
    #pragma unroll
    for (int w2 = 0; w2 < 4; ++w2) {
        int c1 = wc1[w2], c0 = wc0[w2];
        if (w2 < wvi) { off1 += c1; off0 += c0; }
        cnt += c1;
    }
    if (valid) {
        if (mk) jlist[off1 + __popcll(b1 & below)] = t;
        else    jlist[cnt + off0 + __popcll(b0 & below)] = t;
    }
    __syncthreads();

    // ---- K-dot: s[j] = q . k_j (+ c bias for rel heads) ----
    float cval = isrel ? cb[(b * 2 + hr) * NT + i] : 0.0f;
    if (t < NT) {
        const float* krow = isrel ? (kp + ((size_t)(b * NT + t)) * ND + h * NDK)
                                  : (ka + ((size_t)(b * 2 + h) * NT + t) * NDK);
        const float4* k4 = (const float4*)krow;
        const float4* q4 = (const float4*)qrow;
        float acc = cval;
        #pragma unroll
        for (int q = 0; q < 8; ++q) {
            float4 kv = k4[q]; float4 qv = q4[q];
            acc += kv.x * qv.x + kv.y * qv.y + kv.z * qv.z + kv.w * qv.w;
        }
        s[t] = acc;
    } else {
        s[t] = -INFINITY;
    }

    // ---- rel stream over compacted rows: full chunks of 40, exact tail ----
    if (isrel) {
        int half = (lane >> 5), l32 = t & 31;
        int grp = wvi * 2 + half;          // 0..7
        const f32x4* u4g = (const f32x4*)(u + ((size_t)(b * 2 + hr) * NT + i) * ND);
        f32x4 ur = u4g[l32];
        const f32x4* rel4 =
            (const f32x4*)(rel + ((((size_t)hr * NB + b) * NT + i) * (size_t)NT) * ND);
        int cnt40 = cnt - (cnt % 40);
        #pragma unroll 1
        for (int base = 0; base + 40 <= cnt; base += 40) {
            int j0 = jlist[base + grp];
            int j1 = jlist[base + grp + 8];
            int j2 = jlist[base + grp + 16];
            int j3 = jlist[base + grp + 24];
            int j4 = jlist[base + grp + 32];
            f32x4 rv0 = __builtin_nontemporal_load(rel4 + (size_t)j0 * 32 + l32);
            f32x4 rv1 = __builtin_nontemporal_load(rel4 + (size_t)j1 * 32 + l32);
            f32x4 rv2 = __builtin_nontemporal_load(rel4 + (size_t)j2 * 32 + l32);
            f32x4 rv3 = __builtin_nontemporal_load(rel4 + (size_t)j3 * 32 + l32);
            f32x4 rv4 = __builtin_nontemporal_load(rel4 + (size_t)j4 * 32 + l32);
            float p0 = rv0.x*ur.x + rv0.y*ur.y + rv0.z*ur.z + rv0.w*ur.w;
            p0 += __shfl_xor(p0, 16, 32); p0 += __shfl_xor(p0, 8, 32);
            if (l32 < 8) part[j0][l32] = p0;
            float p1 = rv1.x*ur.x + rv1.y*ur.y + rv1.z*ur.z + rv1.w*ur.w;
            p1 += __shfl_xor(p1, 16, 32); p1 += __shfl_xor(p1, 8, 32);
            if (l32 < 8) part[j1][l32] = p1;
            float p2 = rv2.x*ur.x + rv2.y*ur.y + rv2.z*ur.z + rv2.w*ur.w;
            p2 += __shfl_xor(p2, 16, 32); p2 += __shfl_xor(p2, 8, 32);
            if (l32 < 8) part[j2][l32] = p2;
            float p3 = rv3.x*ur.x + rv3.y*ur.y + rv3.z*ur.z + rv3.w*ur.w;
            p3 += __shfl_xor(p3, 16, 32); p3 += __shfl_xor(p3, 8, 32);
            if (l32 < 8) part[j3][l32] = p3;
            float p4 = rv4.x*ur.x + rv4.y*ur.y + rv4.z*ur.z + rv4.w*ur.w;
            p4 += __shfl_xor(p4, 16, 32); p4 += __shfl_xor(p4, 8, 32);
            if (l32 < 8) part[j4][l32] = p4;
        }
        // exact tail: rows [cnt40, cnt), one row per group per iter
        #pragma unroll 1
        for (int idx = cnt40 + grp; idx < cnt; idx += 8) {
            int j = jlist[idx];
            f32x4 rv = __builtin_nontemporal_load(rel4 + (size_t)j * 32 + l32);
            float p = rv.x*ur.x + rv.y*ur.y + rv.z*ur.z + rv.w*ur.w;
            p += __shfl_xor(p, 16, 32); p += __shfl_xor(p, 8, 32);
            if (l32 < 8) part[j][l32] = p;
        }
        __syncthreads();
        if (t < NT && mk != 0) {   // masked rows skip (part[] stale there)
            s[t] += part[t][0] + part[t][1] + part[t][2] + part[t][3]
                  + part[t][4] + part[t][5] + part[t][6] + part[t][7];
        }
    }
    __syncthreads();

    // ---- scale then mask (matches reference order) ----
    if (t < NT) {
        float val = s[t] * 0.17677669529663687f;   // 1/sqrt(32)
        if (mk == 0) val = -1.0e9f;
        s[t] = val;
    }
    __syncthreads();

    // ---- softmax over 256 slots (pad = -inf -> exp 0) ----
    float sv = s[t];
    float m = sv;
    #pragma unroll
    for (int dd = 32; dd >= 1; dd >>= 1) m = fmaxf(m, __shfl_xor(m, dd, 64));
    if ((t & 63) == 0) redm[t >> 6] = m;
    __syncthreads();
    m = fmaxf(fmaxf(redm[0], redm[1]), fmaxf(redm[2], redm[3]));
    float e = expf(sv - m);
    float ssum = e;
    #pragma unroll
    for (int dd = 32; dd >= 1; dd >>= 1) ssum += __shfl_xor(ssum, dd, 64);
    if ((t & 63) == 0) reds[t >> 6] = ssum;
    __syncthreads();
    float tot = reds[0] + reds[1] + reds[2] + reds[3];
    s[t] = e / tot;
    __syncthreads();

    // ---- PV: x[o] = sum_j p[j] * v[b, j, h*32+o] ----
    int o = t & 31, g = t >> 5;
    float acc2 = 0.0f;
    const float* vb = vp + (size_t)b * NT * ND + h * NDK + o;
    for (int j = g; j < NT; j += 8) acc2 += s[j] * vb[(size_t)j * ND];
    xred[t] = acc2;
    __syncthreads();
    if (t < 32) {
        float r = 0.0f;
        #pragma unroll
        for (int g2 = 0; g2 < 8; ++g2) r += xred[g2 * 32 + t];
        xb[((size_t)(b * NT + i)) * ND + h * NDK + t] = r;
    }
}

// ---------------------------------------------------------------------------
// Kernel 5: output projection.  out = xb @ Wo + bo.
// ---------------------------------------------------------------------------
__global__ __launch_bounds__(128) void out_proj_k(
    const float* __restrict__ xb, const float* __restrict__ Wo,
    const float* __restrict__ bo, float* __restrict__ out)
{
    __shared__ float xs[4][128];
    int t = threadIdx.x;
    int g0 = blockIdx.x * 4;
    for (int r = 0; r < 4; ++r) xs[r][t] = xb[(size_t)(g0 + r) * ND + t];
    __syncthreads();
    float bb = bo[t];
    float acc[4];
    for (int r = 0; r < 4; ++r) acc[r] = bb;
    for (int d = 0; d < 128; ++d) {
        float wv = Wo[d * ND + t];
        #pragma unroll
        for (int r = 0; r < 4; ++r) acc[r] += xs[r][d] * wv;
    }
    for (int r = 0; r < 4; ++r) out[(size_t)(g0 + r) * ND + t] = acc[r];
}

// ---------------------------------------------------------------------------
extern "C" void kernel_launch(void* const* d_in, const int* in_sizes, int n_in,
                              void* d_out, int out_size, void* d_ws, size_t ws_size,
                              hipStream_t stream)
{
    const float* query = (const float*)d_in[0];
    const float* key_  = (const float*)d_in[1];
    const float* value = (const float*)d_in[2];
    const int*   mask  = (const int*)  d_in[3];
    const float* rel   = (const float*)d_in[4];
    const float* absk  = (const float*)d_in[5];
    // d_in[6] = layer (unused by reference)
    const float* Wq = (const float*)d_in[7];
    const float* bq = (const float*)d_in[8];
    const float* Wk = (const float*)d_in[9];
    const float* bk = (const float*)d_in[10];
    const float* Wv = (const float*)d_in[11];
    const float* bv = (const float*)d_in[12];
    const float* aqw = (const float*)d_in[13];
    const float* aqb = (const float*)d_in[14];
    const float* akw = (const float*)d_in[15];
    const float* akb = (const float*)d_in[16];
    const float* rkw = (const float*)d_in[17];
    const float* rkb = (const float*)d_in[18];
    const float* rbias = (const float*)d_in[19];
    const float* Wo = (const float*)d_in[20];
    const float* bo = (const float*)d_in[21];
    float* out = (float*)d_out;

    // workspace layout (floats)
    float* qp = (float*)d_ws;          // 409600  (B,T,D)
    float* kp = qp + 409600;           // 409600
    float* vp = kp + 409600;           // 409600
    float* qa = vp + 409600;           // 204800  (B,2,T,32)
    float* ka = qa + 204800;           // 204800
    float* ub = ka + 204800;           // 819200  (B,2,T,128)
    float* cbw = ub + 819200;          // 6400    (B,2,T)
    float* xb = cbw + 6400;            // 409600  (B,T,D)

    qkv_proj_k<<<NB * NT / 4, 128, 0, stream>>>(query, key_, value,
                                                Wq, bq, Wk, bk, Wv, bv,
                                                qp, kp, vp);
    abs_prep_k<<<NB * NT / 8, 128, 0, stream>>>(absk, aqw, aqb, akw, akb,
                                                qp, kp, qa, ka);
    rel_prep_k<<<NB * NT / 8, 256, 0, stream>>>(qp, rkw, rkb, rbias, ub, cbw);
    attn_core_k<<<NB * NH * NT, 256, 0, stream>>>(qp, kp, vp, qa, ka, ub, cbw,
                                                  mask, rel, xb);
    out_proj_k<<<NB * NT / 4, 128, 0, stream>>>(xb, Wo, bo, out);
}

// Round 10
// 158.851 us; speedup vs baseline: 1.9034x; 1.2858x over previous
//
#include <hip/hip_runtime.h>
#include <math.h>

// Problem constants
#define NB 16
#define NT 200
#define ND 128
#define NH 4
#define NDK 32

typedef float f32x4 __attribute__((ext_vector_type(4)));

// ---------------------------------------------------------------------------
// Kernel 1: FUSED prep.  Per block: 4 (b,i) rows.
//   A) q/k/v = x@W+b   (q,k kept in LDS)
//   B) qa = Xq_a + Pq, ka = Xk_a + Pk   (abs heads)
//   C) u, cb           (rel heads)
// All weight matrices are L2-resident (~290 KB total).
// ---------------------------------------------------------------------------
__global__ __launch_bounds__(128) void prep_k(
    const float* __restrict__ query, const float* __restrict__ key_,
    const float* __restrict__ value, const float* __restrict__ absk,
    const float* __restrict__ Wq, const float* __restrict__ bq,
    const float* __restrict__ Wk, const float* __restrict__ bk,
    const float* __restrict__ Wv, const float* __restrict__ bv,
    const float* __restrict__ aqw, const float* __restrict__ aqb,
    const float* __restrict__ akw, const float* __restrict__ akb,
    const float* __restrict__ rkw, const float* __restrict__ rkb,
    const float* __restrict__ rbias,
    float* __restrict__ qp, float* __restrict__ kp, float* __restrict__ vp,
    float* __restrict__ qa, float* __restrict__ ka,
    float* __restrict__ u,  float* __restrict__ cb)
{
    __shared__ float xq[4][128], xk[4][128], xv[4][128];
    __shared__ float qs[4][128], ks[4][128];
    __shared__ float aks[4][2][128];
    int t = threadIdx.x;
    int g0 = blockIdx.x * 4;

    for (int r = 0; r < 4; ++r) {
        xq[r][t] = query[(size_t)(g0 + r) * ND + t];
        xk[r][t] = key_ [(size_t)(g0 + r) * ND + t];
        xv[r][t] = value[(size_t)(g0 + r) * ND + t];
    }
    for (int r = 0; r < 4; ++r) {
        int g = g0 + r, b = g / NT, i = g % NT;
        #pragma unroll
        for (int h2 = 0; h2 < 2; ++h2)
            aks[r][h2][t] = absk[(((size_t)h2 * NB + b) * NT + i) * ND + t];
    }
    __syncthreads();

    // ---- A: QKV ----
    float aq[4], ak[4], av[4];
    for (int r = 0; r < 4; ++r) { aq[r] = bq[t]; ak[r] = bk[t]; av[r] = bv[t]; }
    for (int d = 0; d < 128; ++d) {
        float wq = Wq[d * ND + t], wk = Wk[d * ND + t], wv = Wv[d * ND + t];
        #pragma unroll
        for (int r = 0; r < 4; ++r) {
            aq[r] += xq[r][d] * wq;
            ak[r] += xk[r][d] * wk;
            av[r] += xv[r][d] * wv;
        }
    }
    for (int r = 0; r < 4; ++r) {
        qp[(size_t)(g0 + r) * ND + t] = aq[r];
        kp[(size_t)(g0 + r) * ND + t] = ak[r];
        vp[(size_t)(g0 + r) * ND + t] = av[r];
        qs[r][t] = aq[r];
        ks[r][t] = ak[r];
    }
    __syncthreads();

    // ---- B: abs-head prep (which x h x o = 2x2x32 = 128 threads) ----
    {
        int which = t >> 6, h = (t >> 5) & 1, o = t & 31;
        const float* w  = which ? akw : aqw;
        const float* bb = which ? akb : aqb;
        float bv2 = bb[h * NDK + o];
        float acc[4];
        for (int r = 0; r < 4; ++r) acc[r] = bv2;
        for (int d = 0; d < 128; ++d) {
            float wv2 = w[((size_t)h * ND + d) * NDK + o];
            #pragma unroll
            for (int r = 0; r < 4; ++r) acc[r] += aks[r][h][d] * wv2;
        }
        float* dst = which ? ka : qa;
        for (int r = 0; r < 4; ++r) {
            int g = g0 + r, b = g / NT, i = g % NT;
            float xval = which ? ks[r][h * NDK + o] : qs[r][h * NDK + o];
            dst[((size_t)(b * 2 + h) * NT + i) * NDK + o] = acc[r] + xval;
        }
    }

    // ---- C: rel-head prep (thread t = output dim d; loop h2) ----
    {
        int d = t;
        #pragma unroll
        for (int h2 = 0; h2 < 2; ++h2) {
            float acc[4] = {0.0f, 0.0f, 0.0f, 0.0f};
            for (int o = 0; o < 32; ++o) {
                float wv2 = rkw[((size_t)h2 * ND + d) * NDK + o];
                float rb  = rbias[h2 * NDK + o];
                #pragma unroll
                for (int r = 0; r < 4; ++r)
                    acc[r] += (qs[r][(2 + h2) * NDK + o] + rb) * wv2;
            }
            for (int r = 0; r < 4; ++r) {
                int g = g0 + r, b = g / NT, i = g % NT;
                u[((size_t)(b * 2 + h2) * NT + i) * ND + d] = acc[r];
            }
        }
        if (t < 8) {     // t = r*2 + h2
            int r = t >> 1, h2 = t & 1;
            float cc = 0.0f;
            for (int o = 0; o < 32; ++o)
                cc += (qs[r][(2 + h2) * NDK + o] + rbias[h2 * NDK + o])
                    * rkb[h2 * NDK + o];
            int g = g0 + r, b = g / NT, i = g % NT;
            cb[(b * 2 + h2) * NT + i] = cc;
        }
    }
}

// ---------------------------------------------------------------------------
// Kernel 2: fused scores + mask + softmax + PV.  One block per (b,h,i).
// R6-proven structure: mask-aware rel stream in chunks of 40 (5-deep nt
// batches per half-wave, 2-step shfl, part[200][9]); compaction only in
// rel blocks (isrel is block-uniform; barriers unconditional).
// ---------------------------------------------------------------------------
__global__ __launch_bounds__(256) void attn_core_k(
    const float* __restrict__ qp, const float* __restrict__ kp,
    const float* __restrict__ vp,
    const float* __restrict__ qa, const float* __restrict__ ka,
    const float* __restrict__ u,  const float* __restrict__ cb,
    const int* __restrict__ mask, const float* __restrict__ rel,
    float* __restrict__ xb)
{
    __shared__ float s[256];
    __shared__ float qrow[32];
    __shared__ float redm[4], reds[4];
    __shared__ float xred[256];
    __shared__ float part[200][9];   // stride-9: conflict-free
    __shared__ int   jlist[200];     // [0,cnt): unmasked j; [cnt,200): masked
    __shared__ int   wc1[4], wc0[4];
    int t = threadIdx.x;
    int bx = blockIdx.x;
    int i  = bx % NT;
    int bh = bx / NT;
    int h  = bh % NH;
    int b  = bh / NH;
    bool isrel = (h >= 2);
    int hr = h - 2;
    int lane = t & 63, wvi = t >> 6;

    // ---- mask row (+ ballot compaction, rel blocks only) ----
    int mk = (t < NT) ? mask[((size_t)b * NT + i) * NT + t] : 0;
    bool valid = (t < NT);
    unsigned long long b1 = 0, b0 = 0;
    if (isrel) {
        b1 = __ballot(valid && (mk != 0));
        b0 = __ballot(valid && (mk == 0));
        if (lane == 63) { wc1[wvi] = __popcll(b1); wc0[wvi] = __popcll(b0); }
    }
    if (t < 32) {
        qrow[t] = isrel ? qp[((size_t)(b * NT + i)) * ND + h * NDK + t]
                        : qa[((size_t)(b * 2 + h) * NT + i) * NDK + t];
    }
    __syncthreads();
    int cnt = 0;
    if (isrel) {
        unsigned long long below = ((unsigned long long)1 << lane) - 1;
        int off1 = 0, off0 = 0;
        #pragma unroll
        for (int w2 = 0; w2 < 4; ++w2) {
            int c1 = wc1[w2], c0 = wc0[w2];
            if (w2 < wvi) { off1 += c1; off0 += c0; }
            cnt += c1;
        }
        if (valid) {
            if (mk) jlist[off1 + __popcll(b1 & below)] = t;
            else    jlist[cnt + off0 + __popcll(b0 & below)] = t;
        }
    }
    __syncthreads();

    // ---- K-dot: s[j] = q . k_j (+ c bias for rel heads) ----
    float cval = isrel ? cb[(b * 2 + hr) * NT + i] : 0.0f;
    if (t < NT) {
        const float* krow = isrel ? (kp + ((size_t)(b * NT + t)) * ND + h * NDK)
                                  : (ka + ((size_t)(b * 2 + h) * NT + t) * NDK);
        const float4* k4 = (const float4*)krow;
        const float4* q4 = (const float4*)qrow;
        float acc = cval;
        #pragma unroll
        for (int q = 0; q < 8; ++q) {
            float4 kv = k4[q]; float4 qv = q4[q];
            acc += kv.x * qv.x + kv.y * qv.y + kv.z * qv.z + kv.w * qv.w;
        }
        s[t] = acc;
    } else {
        s[t] = -INFINITY;
    }

    // ---- rel stream over compacted rows: chunks of 40 (5-deep x 8 grps) ----
    if (isrel) {
        int half = (lane >> 5), l32 = t & 31;
        int grp = wvi * 2 + half;          // 0..7
        const f32x4* u4g = (const f32x4*)(u + ((size_t)(b * 2 + hr) * NT + i) * ND);
        f32x4 ur = u4g[l32];
        const f32x4* rel4 =
            (const f32x4*)(rel + ((((size_t)hr * NB + b) * NT + i) * (size_t)NT) * ND);
        #pragma unroll 1
        for (int base = 0; base < cnt; base += 40) {
            // tail-chunk indices >= cnt hit masked rows of jlist: streamed at
            // most once, their part[] result is dead (score -> -1e9).
            int j0 = jlist[base + grp];
            int j1 = jlist[base + grp + 8];
            int j2 = jlist[base + grp + 16];
            int j3 = jlist[base + grp + 24];
            int j4 = jlist[base + grp + 32];
            f32x4 rv0 = __builtin_nontemporal_load(rel4 + (size_t)j0 * 32 + l32);
            f32x4 rv1 = __builtin_nontemporal_load(rel4 + (size_t)j1 * 32 + l32);
            f32x4 rv2 = __builtin_nontemporal_load(rel4 + (size_t)j2 * 32 + l32);
            f32x4 rv3 = __builtin_nontemporal_load(rel4 + (size_t)j3 * 32 + l32);
            f32x4 rv4 = __builtin_nontemporal_load(rel4 + (size_t)j4 * 32 + l32);
            float p0 = rv0.x*ur.x + rv0.y*ur.y + rv0.z*ur.z + rv0.w*ur.w;
            p0 += __shfl_xor(p0, 16, 32); p0 += __shfl_xor(p0, 8, 32);
            if (l32 < 8) part[j0][l32] = p0;
            float p1 = rv1.x*ur.x + rv1.y*ur.y + rv1.z*ur.z + rv1.w*ur.w;
            p1 += __shfl_xor(p1, 16, 32); p1 += __shfl_xor(p1, 8, 32);
            if (l32 < 8) part[j1][l32] = p1;
            float p2 = rv2.x*ur.x + rv2.y*ur.y + rv2.z*ur.z + rv2.w*ur.w;
            p2 += __shfl_xor(p2, 16, 32); p2 += __shfl_xor(p2, 8, 32);
            if (l32 < 8) part[j2][l32] = p2;
            float p3 = rv3.x*ur.x + rv3.y*ur.y + rv3.z*ur.z + rv3.w*ur.w;
            p3 += __shfl_xor(p3, 16, 32); p3 += __shfl_xor(p3, 8, 32);
            if (l32 < 8) part[j3][l32] = p3;
            float p4 = rv4.x*ur.x + rv4.y*ur.y + rv4.z*ur.z + rv4.w*ur.w;
            p4 += __shfl_xor(p4, 16, 32); p4 += __shfl_xor(p4, 8, 32);
            if (l32 < 8) part[j4][l32] = p4;
        }
        __syncthreads();
        if (t < NT && mk != 0) {   // masked rows skip (part[] may be stale)
            s[t] += part[t][0] + part[t][1] + part[t][2] + part[t][3]
                  + part[t][4] + part[t][5] + part[t][6] + part[t][7];
        }
    }
    __syncthreads();

    // ---- scale then mask (matches reference order) ----
    if (t < NT) {
        float val = s[t] * 0.17677669529663687f;   // 1/sqrt(32)
        if (mk == 0) val = -1.0e9f;
        s[t] = val;
    }
    __syncthreads();

    // ---- softmax over 256 slots (pad = -inf -> exp 0) ----
    float sv = s[t];
    float m = sv;
    #pragma unroll
    for (int dd = 32; dd >= 1; dd >>= 1) m = fmaxf(m, __shfl_xor(m, dd, 64));
    if ((t & 63) == 0) redm[t >> 6] = m;
    __syncthreads();
    m = fmaxf(fmaxf(redm[0], redm[1]), fmaxf(redm[2], redm[3]));
    float e = expf(sv - m);
    float ssum = e;
    #pragma unroll
    for (int dd = 32; dd >= 1; dd >>= 1) ssum += __shfl_xor(ssum, dd, 64);
    if ((t & 63) == 0) reds[t >> 6] = ssum;
    __syncthreads();
    float tot = reds[0] + reds[1] + reds[2] + reds[3];
    s[t] = e / tot;
    __syncthreads();

    // ---- PV: x[o] = sum_j p[j] * v[b, j, h*32+o] ----
    int o = t & 31, g = t >> 5;
    float acc2 = 0.0f;
    const float* vb = vp + (size_t)b * NT * ND + h * NDK + o;
    for (int j = g; j < NT; j += 8) acc2 += s[j] * vb[(size_t)j * ND];
    xred[t] = acc2;
    __syncthreads();
    if (t < 32) {
        float r = 0.0f;
        #pragma unroll
        for (int g2 = 0; g2 < 8; ++g2) r += xred[g2 * 32 + t];
        xb[((size_t)(b * NT + i)) * ND + h * NDK + t] = r;
    }
}

// ---------------------------------------------------------------------------
// Kernel 3: output projection.  out = xb @ Wo + bo.
// ---------------------------------------------------------------------------
__global__ __launch_bounds__(128) void out_proj_k(
    const float* __restrict__ xb, const float* __restrict__ Wo,
    const float* __restrict__ bo, float* __restrict__ out)
{
    __shared__ float xs[4][128];
    int t = threadIdx.x;
    int g0 = blockIdx.x * 4;
    for (int r = 0; r < 4; ++r) xs[r][t] = xb[(size_t)(g0 + r) * ND + t];
    __syncthreads();
    float bb = bo[t];
    float acc[4];
    for (int r = 0; r < 4; ++r) acc[r] = bb;
    for (int d = 0; d < 128; ++d) {
        float wv = Wo[d * ND + t];
        #pragma unroll
        for (int r = 0; r < 4; ++r) acc[r] += xs[r][d] * wv;
    }
    for (int r = 0; r < 4; ++r) out[(size_t)(g0 + r) * ND + t] = acc[r];
}

// ---------------------------------------------------------------------------
extern "C" void kernel_launch(void* const* d_in, const int* in_sizes, int n_in,
                              void* d_out, int out_size, void* d_ws, size_t ws_size,
                              hipStream_t stream)
{
    const float* query = (const float*)d_in[0];
    const float* key_  = (const float*)d_in[1];
    const float* value = (const float*)d_in[2];
    const int*   mask  = (const int*)  d_in[3];
    const float* rel   = (const float*)d_in[4];
    const float* absk  = (const float*)d_in[5];
    // d_in[6] = layer (unused by reference)
    const float* Wq = (const float*)d_in[7];
    const float* bq = (const float*)d_in[8];
    const float* Wk = (const float*)d_in[9];
    const float* bk = (const float*)d_in[10];
    const float* Wv = (const float*)d_in[11];
    const float* bv = (const float*)d_in[12];
    const float* aqw = (const float*)d_in[13];
    const float* aqb = (const float*)d_in[14];
    const float* akw = (const float*)d_in[15];
    const float* akb = (const float*)d_in[16];
    const float* rkw = (const float*)d_in[17];
    const float* rkb = (const float*)d_in[18];
    const float* rbias = (const float*)d_in[19];
    const float* Wo = (const float*)d_in[20];
    const float* bo = (const float*)d_in[21];
    float* out = (float*)d_out;

    // workspace layout (floats)
    float* qp = (float*)d_ws;          // 409600  (B,T,D)
    float* kp = qp + 409600;           // 409600
    float* vp = kp + 409600;           // 409600
    float* qa = vp + 409600;           // 204800  (B,2,T,32)
    float* ka = qa + 204800;           // 204800
    float* ub = ka + 204800;           // 819200  (B,2,T,128)
    float* cbw = ub + 819200;          // 6400    (B,2,T)
    float* xb = cbw + 6400;            // 409600  (B,T,D)

    prep_k<<<NB * NT / 4, 128, 0, stream>>>(query, key_, value, absk,
                                            Wq, bq, Wk, bk, Wv, bv,
                                            aqw, aqb, akw, akb,
                                            rkw, rkb, rbias,
                                            qp, kp, vp, qa, ka, ub, cbw);
    attn_core_k<<<NB * NH * NT, 256, 0, stream>>>(qp, kp, vp, qa, ka, ub, cbw,
                                                  mask, rel, xb);
    out_proj_k<<<NB * NT / 4, 128, 0, stream>>>(xb, Wo, bo, out);
}